// Round 3
// baseline (4421.012 us; speedup 1.0000x reference)
//
#include <hip/hip_runtime.h>
#include <hip/hip_bf16.h>
#include <cfloat>

// Problem constants (fixed by the reference):
//   B_ = 3200, Np1 = 21, Mp1 = 41, C = 400, H = 36, D = 20, H*D = 720
// Workspace layout (needs 668,160,000 bytes):
//   qbuf  : bf16[67200*720]   =  96,768,000 B
//   kvbuf : bf16[131200*1440] = 377,856,000 B
//   abuf  : f32 [67200*720]   = 193,536,000 B

#define TM 64
#define TN 64
#define TK 16

__device__ __forceinline__ float bf2f(__hip_bfloat16 x) { return __bfloat162float(x); }

__device__ __forceinline__ void st1(float* p, float v) { *p = v; }
__device__ __forceinline__ void st1(__hip_bfloat16* p, float v) { *p = __float2bfloat16(v); }

// C[M,N] = A[M,K] @ W[N,K]^T + bias[N]
// Requires: M % TM == 0, K % TK == 0 (true for all three GEMMs here). N guarded.
template <typename OT>
__global__ __launch_bounds__(256) void gemm_bias_kernel(
    const float* __restrict__ A, const float* __restrict__ W,
    const float* __restrict__ bias, OT* __restrict__ C,
    int M, int N, int K) {
  __shared__ float As[TK][TM + 4];
  __shared__ float Ws[TK][TN + 4];
  const int tid = threadIdx.x;
  const int tx = tid & 15, ty = tid >> 4;
  const int m0 = blockIdx.x * TM;
  const int n0 = blockIdx.y * TN;

  float acc[4][4] = {{0.f}};

  const int r  = tid >> 2;        // 0..63  (row within tile)
  const int kq = (tid & 3) * 4;   // 0,4,8,12 (k within tile)

  for (int k0 = 0; k0 < K; k0 += TK) {
    // A tile: 64 rows x 16 k, one float4 per thread
    {
      float4 v = *reinterpret_cast<const float4*>(A + (size_t)(m0 + r) * K + k0 + kq);
      As[kq + 0][r] = v.x; As[kq + 1][r] = v.y; As[kq + 2][r] = v.z; As[kq + 3][r] = v.w;
    }
    // W tile: 64 n-rows x 16 k, guarded on N
    {
      int n = n0 + r;
      float4 v = make_float4(0.f, 0.f, 0.f, 0.f);
      if (n < N) v = *reinterpret_cast<const float4*>(W + (size_t)n * K + k0 + kq);
      Ws[kq + 0][r] = v.x; Ws[kq + 1][r] = v.y; Ws[kq + 2][r] = v.z; Ws[kq + 3][r] = v.w;
    }
    __syncthreads();
#pragma unroll
    for (int kk = 0; kk < TK; ++kk) {
      float4 a = *reinterpret_cast<const float4*>(&As[kk][ty * 4]);
      float4 w = *reinterpret_cast<const float4*>(&Ws[kk][tx * 4]);
      float av[4] = {a.x, a.y, a.z, a.w};
      float wv[4] = {w.x, w.y, w.z, w.w};
#pragma unroll
      for (int i = 0; i < 4; ++i)
#pragma unroll
        for (int j = 0; j < 4; ++j)
          acc[i][j] += av[i] * wv[j];
    }
    __syncthreads();
  }

#pragma unroll
  for (int i = 0; i < 4; ++i) {
    int m = m0 + ty * 4 + i;
#pragma unroll
    for (int j = 0; j < 4; ++j) {
      int n = n0 + tx * 4 + j;
      if (n < N) st1(C + (size_t)m * N + n, acc[i][j] + bias[n]);
    }
  }
}

// One block per (window b, head h): scores -> bias -> mask -> softmax -> PV
__global__ __launch_bounds__(256) void attn_kernel(
    const __hip_bfloat16* __restrict__ qbuf, const __hip_bfloat16* __restrict__ kvbuf,
    const int* __restrict__ mask_left, const int* __restrict__ mask_right,
    const int* __restrict__ nWp,
    const float* __restrict__ rel_table, const float* __restrict__ cls_up,
    const float* __restrict__ cls_down, const float* __restrict__ cls_self,
    float* __restrict__ abuf, int mrowsL, int mrowsR) {
  constexpr int Np1 = 21, Mp1 = 41, D = 20, H = 36, HD = 720, HD2 = 1440;
  __shared__ float qs[Np1][D];
  __shared__ float ks[Mp1][D];
  __shared__ float vs[Mp1][D];
  __shared__ float sc[Np1][Mp1];

  const int b = blockIdx.x;
  const int h = blockIdx.y;
  const int tid = threadIdx.x;

  for (int idx = tid; idx < Np1 * D; idx += 256) {
    int n = idx / D, d = idx % D;
    qs[n][d] = bf2f(qbuf[((size_t)b * Np1 + n) * HD + h * D + d]);
  }
  for (int idx = tid; idx < Mp1 * D; idx += 256) {
    int m = idx / D, d = idx % D;
    size_t base = ((size_t)b * Mp1 + m) * HD2 + h * D + d;
    ks[m][d] = bf2f(kvbuf[base]);
    vs[m][d] = bf2f(kvbuf[base + HD]);
  }
  __syncthreads();

  const int nW = nWp[0];
  const int w = b % nW;
  const int mcL = (mrowsL < nW) ? mrowsL : nW;
  const int mcR = (mrowsR < nW) ? mrowsR : nW;
  const float scale = 0.22360679774997896f;  // 1/sqrt(20)

  for (int idx = tid; idx < Np1 * Mp1; idx += 256) {
    int i = idx / Mp1, j = idx % Mp1;
    float s = 0.f;
#pragma unroll
    for (int dd = 0; dd < D; dd += 4) {
      float4 qa = *reinterpret_cast<const float4*>(&qs[i][dd]);
      float4 kb = *reinterpret_cast<const float4*>(&ks[j][dd]);
      s += qa.x * kb.x + qa.y * kb.y + qa.z * kb.z + qa.w * kb.w;
    }
    s *= scale;
    float bv;
    if (i == 0 && j == 0)      bv = cls_self[h];
    else if (i == 0)           bv = cls_up[h * (Mp1 - 1) + (j - 1)];
    else if (j == 0)           bv = cls_down[h * (Np1 - 1) + (i - 1)];
    else                       bv = rel_table[(i - j + 39) * H + h];
    s += bv;
    if (w < mcL && mask_left[w * Np1 * Mp1 + idx] == 1) s = -FLT_MAX;
    if (w >= nW - mcR) {
      int mrow = (mrowsR - mcR) + (w - (nW - mcR));
      if (mask_right[mrow * Np1 * Mp1 + idx] == 1) s = -FLT_MAX;
    }
    sc[i][j] = s;
  }
  __syncthreads();

  // softmax: one row per wave, strided
  const int wv = tid >> 6, ln = tid & 63;
  for (int rrow = wv; rrow < Np1; rrow += 4) {
    float v = (ln < Mp1) ? sc[rrow][ln] : -FLT_MAX;
    float mx = v;
#pragma unroll
    for (int o = 32; o > 0; o >>= 1) mx = fmaxf(mx, __shfl_xor(mx, o));
    float e = (ln < Mp1) ? __expf(v - mx) : 0.f;
    float sum = e;
#pragma unroll
    for (int o = 32; o > 0; o >>= 1) sum += __shfl_xor(sum, o);
    if (ln < Mp1) sc[rrow][ln] = e / sum;
  }
  __syncthreads();

  for (int idx = tid; idx < Np1 * D; idx += 256) {
    int n = idx / D, d = idx % D;
    float acc = 0.f;
#pragma unroll
    for (int m = 0; m < Mp1; ++m) acc += sc[n][m] * vs[m][d];
    abuf[((size_t)b * Np1 + n) * HD + h * D + d] = acc;
  }
}

// proj GEMM reading f32 A is gemm_bias_kernel<float> with A = abuf.

extern "C" void kernel_launch(void* const* d_in, const int* in_sizes, int n_in,
                              void* d_out, int out_size, void* d_ws, size_t ws_size,
                              hipStream_t stream) {
  const float* x         = (const float*)d_in[0];
  const float* x_        = (const float*)d_in[1];
  const int*   mask_left = (const int*)d_in[2];
  const int*   mask_right= (const int*)d_in[3];
  const int*   nWp       = (const int*)d_in[4];
  const float* Wq        = (const float*)d_in[5];
  const float* bq        = (const float*)d_in[6];
  const float* Wkv       = (const float*)d_in[7];
  const float* bkv       = (const float*)d_in[8];
  const float* Wproj     = (const float*)d_in[9];
  const float* bproj     = (const float*)d_in[10];
  const float* rel_table = (const float*)d_in[11];
  const float* cls_up    = (const float*)d_in[12];
  const float* cls_down  = (const float*)d_in[13];
  const float* cls_self  = (const float*)d_in[14];
  float* out = (float*)d_out;

  const int Np1 = 21, Mp1 = 41, C = 400, HD = 720, HD2 = 1440;
  const int B_ = in_sizes[0] / (Np1 * C);       // 3200
  const int M1 = B_ * Np1;                      // 67200
  const int M2 = B_ * Mp1;                      // 131200
  const int mrowsL = in_sizes[2] / (Np1 * Mp1); // 2
  const int mrowsR = in_sizes[3] / (Np1 * Mp1); // 2

  char* wsp = (char*)d_ws;
  __hip_bfloat16* qbuf  = (__hip_bfloat16*)wsp;
  size_t qBytes  = (size_t)M1 * HD * sizeof(__hip_bfloat16);
  __hip_bfloat16* kvbuf = (__hip_bfloat16*)(wsp + qBytes);
  size_t kvBytes = (size_t)M2 * HD2 * sizeof(__hip_bfloat16);
  float* abuf = (float*)(wsp + qBytes + kvBytes);

  // GEMM1: q = x @ Wq^T + bq   (67200 x 720 x 400), bf16 out
  gemm_bias_kernel<__hip_bfloat16>
      <<<dim3(M1 / TM, (HD + TN - 1) / TN), 256, 0, stream>>>(x, Wq, bq, qbuf, M1, HD, C);
  // GEMM2: kv = x_ @ Wkv^T + bkv (131200 x 1440 x 400), bf16 out
  gemm_bias_kernel<__hip_bfloat16>
      <<<dim3(M2 / TM, (HD2 + TN - 1) / TN), 256, 0, stream>>>(x_, Wkv, bkv, kvbuf, M2, HD2, C);
  // Fused attention per (window, head)
  attn_kernel<<<dim3(B_, 36), 256, 0, stream>>>(
      qbuf, kvbuf, mask_left, mask_right, nWp,
      rel_table, cls_up, cls_down, cls_self, abuf, mrowsL, mrowsR);
  // GEMM3: out = abuf @ Wproj^T + bproj (67200 x 400 x 720), f32 out
  gemm_bias_kernel<float>
      <<<dim3(M1 / TM, (C + TN - 1) / TN), 256, 0, stream>>>(abuf, Wproj, bproj, out, M1, C, HD);
}